// Round 12
// baseline (77.042 us; speedup 1.0000x reference)
//
#include <hip/hip_runtime.h>

typedef _Float16 f16;
typedef f16 f16x8 __attribute__((ext_vector_type(8)));
typedef float f32x4 __attribute__((ext_vector_type(4)));
typedef float f32x2 __attribute__((ext_vector_type(2)));
typedef unsigned u32;

#define MFMA16(a, b, c) __builtin_amdgcn_mfma_f32_16x16x32_f16(a, b, c, 0, 0, 0)

// packed-weight offsets in f16 elements within d_ws (16x16x32 frag layout)
// RW1|RW2|RW3 contiguous 90KB at 0; QW2|QW3 70KB at OFF_QW2; PW2|PW3 70KB at OFF_PW2.
#define OFF_RW1A 0
#define OFF_RW2  10240
#define OFF_RW3  35840
#define OFF_QW1  46080
#define OFF_QW2  87040
#define OFF_QW3  112640
#define OFF_PW1  122880
#define OFF_PW2  163840
#define OFF_PW3  189440
#define PACK_BYTES 399360   // 199680 f16

// prep grid: [0,256) red0 partials | [256,355) pack | [355,363) qmax
//            [363,371) e1q | [371,627) c1/d1 | [627,1651) red1
#define PREP_BLOCKS 1651

struct InPtrs { const float* p[21]; };

__device__ const int g_mSrc[9] = {15, 17, 19, 9, 11, 13, 3, 5, 7};
__device__ const int g_mK0[9]  = {0, 0, 0, 128, 0, 0, 0, 0, 0};
__device__ const int g_mK[9]   = {64, 132, 132, 256, 132, 132, 256, 132, 132};
__device__ const int g_mN[9]   = {132, 132, 64, 132, 132, 64, 132, 132, 64};
__device__ const int g_mNT[9]  = {10, 10, 4, 10, 10, 4, 10, 10, 4};
__device__ const int g_mDst[9] = {OFF_RW1A, OFF_RW2, OFF_RW3, OFF_QW1, OFF_QW2, OFF_QW3,
                                  OFF_PW1, OFF_PW2, OFF_PW3};
__device__ const int g_mBlk0[9] = {256, 261, 274, 279, 299, 312, 317, 337, 350};

__global__ __launch_bounds__(256) void prep_kernel(InPtrs in, f16* __restrict__ wpk,
    float* __restrict__ c1, float* __restrict__ d1, float* __restrict__ e1q,
    float* __restrict__ qmax, float* __restrict__ red0p, float* __restrict__ red1)
{
  __shared__ float sbuf[1024];
  const int mb = blockIdx.x, t = threadIdx.x;

  if (mb < 256) {
    // red0 partial: max over 64 i's; block = (b, j-oct, i-half). Contiguous 2KB/i.
    const int b = mb >> 5, jo = (mb >> 1) & 15, ih = mb & 1;
    const float* base = in.p[2] + (size_t)b * 1048576 + (size_t)ih * 64 * 8192
                        + (size_t)jo * 512 + t * 2;
    f32x2 m[8];
    #pragma unroll
    for (int u = 0; u < 8; ++u) { m[u][0] = -3.4e38f; m[u][1] = -3.4e38f; }
    for (int i = 0; i < 64; i += 8) {
      #pragma unroll
      for (int u = 0; u < 8; ++u) {
        f32x2 v = *(const f32x2*)(base + (size_t)(i + u) * 8192);
        m[u][0] = fmaxf(m[u][0], v[0]);
        m[u][1] = fmaxf(m[u][1], v[1]);
      }
    }
    #pragma unroll
    for (int s = 4; s > 0; s >>= 1)
      #pragma unroll
      for (int u = 0; u < 4; ++u)
        if (u < s) {
          m[u][0] = fmaxf(m[u][0], m[u + s][0]);
          m[u][1] = fmaxf(m[u][1], m[u + s][1]);
        }
    *(f32x2*)(red0p + (size_t)ih * 65536 +
              ((size_t)(b * 128 + jo * 8 + (t >> 5))) * 64 + ((t * 2) & 63)) = m[0];
  } else if (mb < 355) {
    // weight pack into 16x16x32 MFMA fragment layout
    int mi = 8;
    while (mi > 0 && mb < g_mBlk0[mi]) --mi;
    const int NT = g_mNT[mi], K = g_mK[mi], N = g_mN[mi], K0 = g_mK0[mi];
    const int L = (mb - g_mBlk0[mi]) * 256 + t;
    const int lanes = ((K + 31) >> 5) * NT * 64;
    if (L < lanes) {
      const int lane = L & 63, tile = L >> 6;
      const int kk = tile / NT, nn = tile % NT;
      const float* src = in.p[g_mSrc[mi]];
      const int n = nn * 16 + (lane & 15);
      const int kb = kk * 32 + ((lane >> 4) << 3);
      f16x8 v;
      #pragma unroll
      for (int u = 0; u < 8; ++u) {
        const int k = kb + u;
        float f = (k < K && n < N) ? src[(size_t)(K0 + k) * N + n] : 0.f;
        v[u] = (f16)f;
      }
      *(f16x8*)(wpk + g_mDst[mi] + (size_t)L * 8) = v;
    }
  } else if (mb < 363) {
    // qmax[b,d] = max_i Q[b,i,d]
    const int b = mb - 355;
    const float* Qb = in.p[1] + (size_t)b * 128 * 128;
    const int d = t & 127, g = t >> 7;
    float m0 = -3.4e38f, m1 = m0, m2 = m0, m3 = m0;
    #pragma unroll
    for (int v = 0; v < 16; ++v) {
      const int i = g * 64 + v * 4;
      m0 = fmaxf(m0, Qb[(size_t)(i + 0) * 128 + d]);
      m1 = fmaxf(m1, Qb[(size_t)(i + 1) * 128 + d]);
      m2 = fmaxf(m2, Qb[(size_t)(i + 2) * 128 + d]);
      m3 = fmaxf(m3, Qb[(size_t)(i + 3) * 128 + d]);
    }
    sbuf[g * 128 + d] = fmaxf(fmaxf(m0, m1), fmaxf(m2, m3));
    __syncthreads();
    if (t < 128) qmax[b * 128 + t] = fmaxf(sbuf[t], sbuf[128 + t]);
  } else if (mb < 371) {
    // e1q[b,n] = P[b] . q_w1[0:128] + q_b1
    const int b = mb - 363;
    const float* P = in.p[0]; const float* qw1 = in.p[9]; const float* qb1 = in.p[10];
    if (t < 160) {
      float a = 0.f;
      if (t < 132) {
        float a0 = 0.f, a1 = 0.f, a2 = 0.f, a3 = 0.f;
        for (int k = 0; k < 128; k += 4) {
          a0 += P[b * 128 + k + 0] * qw1[(size_t)(k + 0) * 132 + t];
          a1 += P[b * 128 + k + 1] * qw1[(size_t)(k + 1) * 132 + t];
          a2 += P[b * 128 + k + 2] * qw1[(size_t)(k + 2) * 132 + t];
          a3 += P[b * 128 + k + 3] * qw1[(size_t)(k + 3) * 132 + t];
        }
        a = qb1[t] + (a0 + a1) + (a2 + a3);
      }
      e1q[b * 160 + t] = a;
    }
  } else if (mb < 627) {
    // c1/d1 (r-branch folded Q contributions), 4 Q-rows per block
    const int blk = mb - 371;
    const float* Q = in.p[1]; const float* rw1 = in.p[15]; const float* rb1 = in.p[16];
    for (int o = t; o < 512; o += 256) sbuf[o] = Q[(size_t)blk * 512 + o];
    __syncthreads();
    if (t < 160) {
      float cc[4], dd[4];
      #pragma unroll
      for (int r = 0; r < 4; ++r) { cc[r] = 0.f; dd[r] = 0.f; }
      if (t < 132) {
        const float bb = rb1[t];
        #pragma unroll
        for (int r = 0; r < 4; ++r) cc[r] = bb;
        for (int k = 0; k < 128; ++k) {
          const float wc = rw1[(size_t)(192 + k) * 132 + t];
          const float wd = rw1[(size_t)(64 + k) * 132 + t];
          #pragma unroll
          for (int r = 0; r < 4; ++r) {
            cc[r] += sbuf[r * 128 + k] * wc;
            dd[r] += sbuf[r * 128 + k] * wd;
          }
        }
      }
      for (int r = 0; r < 4; ++r) {
        c1[(size_t)(blk * 4 + r) * 160 + t] = cc[r];
        d1[(size_t)(blk * 4 + r) * 160 + t] = dd[r];
      }
    }
  } else {
    // red1[b,i,d] = max_j R[b,i,j,d]; one block per (b,i); contiguous loads.
    const int bi = mb - 627;
    const int d2 = t & 31, jg = t >> 5;
    const float* base = in.p[2] + (size_t)bi * 8192 + (size_t)jg * 1024 + d2 * 2;
    f32x2 m[4];
    #pragma unroll
    for (int u = 0; u < 4; ++u) { m[u][0] = -3.4e38f; m[u][1] = -3.4e38f; }
    #pragma unroll
    for (int v = 0; v < 16; v += 4) {
      #pragma unroll
      for (int u = 0; u < 4; ++u) {
        f32x2 vv = *(const f32x2*)(base + (size_t)(v + u) * 64);
        m[u][0] = fmaxf(m[u][0], vv[0]);
        m[u][1] = fmaxf(m[u][1], vv[1]);
      }
    }
    m[0][0] = fmaxf(fmaxf(m[0][0], m[1][0]), fmaxf(m[2][0], m[3][0]));
    m[0][1] = fmaxf(fmaxf(m[0][1], m[1][1]), fmaxf(m[2][1], m[3][1]));
    sbuf[jg * 64 + d2 * 2] = m[0][0];
    sbuf[jg * 64 + d2 * 2 + 1] = m[0][1];
    __syncthreads();
    if (t < 64) {
      float mm = sbuf[t];
      #pragma unroll
      for (int g2 = 1; g2 < 8; ++g2) mm = fmaxf(mm, sbuf[g2 * 64 + t]);
      red1[(size_t)bi * 64 + t] = mm;
    }
  }
}

__device__ __forceinline__ float sig5(float x) {
  return 1.f / (1.f + __expf(-5.f * x));
}

__device__ __forceinline__ u32 pk2(float a, float b) {
  typedef __fp16 fp16x2 __attribute__((ext_vector_type(2)));
  union { fp16x2 h; u32 u; } cv;
  cv.h = __builtin_amdgcn_cvt_pkrtz(a, b);
  return cv.u;
}

__device__ __forceinline__ f16x8 ld8(const float* p) {
  f32x4 v0 = *(const f32x4*)p, v1 = *(const f32x4*)(p + 4);
  union { u32 w[4]; f16x8 v; } U;
  U.w[0] = pk2(v0[0], v0[1]); U.w[1] = pk2(v0[2], v0[3]);
  U.w[2] = pk2(v1[0], v1[1]); U.w[3] = pk2(v1[2], v1[3]);
  return U.v;
}

__device__ __forceinline__ f16x8 ld8max(const float* p, int stride) {
  f32x4 a0 = *(const f32x4*)p, a1 = *(const f32x4*)(p + 4);
  f32x4 b0 = *(const f32x4*)(p + stride), b1 = *(const f32x4*)(p + stride + 4);
  union { u32 w[4]; f16x8 v; } U;
  U.w[0] = pk2(fmaxf(a0[0], b0[0]), fmaxf(a0[1], b0[1]));
  U.w[1] = pk2(fmaxf(a0[2], b0[2]), fmaxf(a0[3], b0[3]));
  U.w[2] = pk2(fmaxf(a1[0], b1[0]), fmaxf(a1[1], b1[1]));
  U.w[3] = pk2(fmaxf(a1[2], b1[2]), fmaxf(a1[3], b1[3]));
  return U.v;
}

// Layer-transition: build next-layer B-frag from two D-tiles entirely in regs.
// dest lane (g,i) word pair u/4: from lane ((2g + u/4)&3)*16 + i, tile 2c+(g>>1).
__device__ __forceinline__ f16x8 make_bfrag(const f32x4 ta, const f32x4 tb,
                                            int srcA, int srcB, bool glo) {
  u32 a0 = pk2(fmaxf(ta[0], 0.f), fmaxf(ta[1], 0.f));
  u32 a1 = pk2(fmaxf(ta[2], 0.f), fmaxf(ta[3], 0.f));
  u32 b0 = pk2(fmaxf(tb[0], 0.f), fmaxf(tb[1], 0.f));
  u32 b1 = pk2(fmaxf(tb[2], 0.f), fmaxf(tb[3], 0.f));
  u32 aA0 = (u32)__shfl((int)a0, srcA), aA1 = (u32)__shfl((int)a1, srcA);
  u32 bA0 = (u32)__shfl((int)b0, srcA), bA1 = (u32)__shfl((int)b1, srcA);
  u32 aB0 = (u32)__shfl((int)a0, srcB), aB1 = (u32)__shfl((int)a1, srcB);
  u32 bB0 = (u32)__shfl((int)b0, srcB), bB1 = (u32)__shfl((int)b1, srcB);
  union { u32 w[4]; f16x8 v; } U;
  U.w[0] = glo ? aA0 : bA0;
  U.w[1] = glo ? aA1 : bA1;
  U.w[2] = glo ? aB0 : bB0;
  U.w[3] = glo ? aB1 : bB1;
  return U.v;
}

// ---------------------------------------------------------------------------
// fused kernel: 517 blocks x 512 threads (8 waves), launch_bounds(512,2)
// (LDS caps residency at 1 block/CU; reg cap 256 -> no forced spill).
// Stage branch weights into LDS ONCE (R: W1|W2|W3 90KB; Q/P: W2|W3 70KB),
// one barrier, then each wave runs the R7-verified barrier-free 32-row body
// (acc[2][10], in-register make_bfrag transitions) with weight frags via
// ds_read_b128 (~120cy) instead of L2 loads (~600cy) -> 5x shorter chain.
// Blocks [0,4): Q (8 chunks of 32 rows each); block 4: P; [5,517): R (2 bi).
// ---------------------------------------------------------------------------
__global__ __launch_bounds__(512, 2) void fused_kernel(
    const float* __restrict__ R, const float* __restrict__ c1, const float* __restrict__ d1,
    const float* __restrict__ rb2, const float* __restrict__ rb3,
    const f16* __restrict__ wpk, float* __restrict__ outR,
    const float* __restrict__ P, const float* __restrict__ Q,
    const float* __restrict__ qb2, const float* __restrict__ qb3,
    const float* __restrict__ pb1, const float* __restrict__ pb2, const float* __restrict__ pb3,
    const float* __restrict__ e1q, const float* __restrict__ qmax,
    const float* __restrict__ red0p, const float* __restrict__ red1,
    float* __restrict__ outP, float* __restrict__ outQ)
{
  __shared__ f16 Wb[46080];   // 90 KB
  const int t = threadIdx.x, lane = t & 63, w = t >> 6;
  const int g = lane >> 4, i = lane & 15;
  const int nrow = g * 4;
  const bool glo = (g < 2);
  const int srcA = ((2 * g) & 3) * 16 + i;
  const int srcB = ((2 * g + 1) & 3) * 16 + i;
  const int bk = blockIdx.x;
  const bool isR = (bk >= 5);
  const bool isP = (bk == 4);

  {
    const f16* src = isR ? wpk : (isP ? (wpk + OFF_PW2) : (wpk + OFF_QW2));
    const int total = isR ? 46080 : 35840;
    for (int idx = t * 8; idx < total; idx += 4096)
      *(f16x8*)(&Wb[idx]) = *(const f16x8*)(src + idx);
  }
  __syncthreads();

  const f16x8* W2L = (const f16x8*)(Wb + (isR ? 10240 : 0));
  const f16x8* W3L = (const f16x8*)(Wb + (isR ? 35840 : 25600));

  f32x4 acc[2][10];
  const float *b2p, *b3p;
  float* obase;
  int rowlim;

  if (isR) {
    // ================= R branch L1 (K=64), W1 from LDS =================
    const int idx = bk - 5;
    const int bi = idx * 2 + (w >> 2), rowbase = (w & 3) * 32;
    const int b = bi >> 7;
    const float* c1r = c1 + (size_t)bi * 160;
    const float* d1b = d1 + ((size_t)(b * 128 + rowbase)) * 160;
    #pragma unroll
    for (int tn = 0; tn < 10; ++tn) {
      const f32x4 cv = *(const f32x4*)(c1r + tn * 16 + nrow);
      #pragma unroll
      for (int tj = 0; tj < 2; ++tj)
        acc[tj][tn] = cv + *(const f32x4*)(d1b + (size_t)(tj * 16 + i) * 160 + tn * 16 + nrow);
    }
    const f16x8* W1L = (const f16x8*)(Wb);
    const float* Rb = R + (size_t)bi * 8192 + (size_t)rowbase * 64;
    #pragma unroll
    for (int c = 0; c < 2; ++c) {
      const f16x8 x0 = ld8(Rb + (size_t)i * 64 + c * 32 + g * 8);
      const f16x8 x1 = ld8(Rb + (size_t)(16 + i) * 64 + c * 32 + g * 8);
      #pragma unroll
      for (int tn = 0; tn < 10; ++tn) {
        const f16x8 bf = W1L[(size_t)(c * 10 + tn) * 64 + lane];
        acc[0][tn] = MFMA16(bf, x0, acc[0][tn]);
        acc[1][tn] = MFMA16(bf, x1, acc[1][tn]);
      }
    }
    b2p = rb2; b3p = rb3;
    obase = outR + (size_t)bi * 8192 + (size_t)rowbase * 64;
    rowlim = 32;
  } else if (!isP) {
    // ================= Q branch L1 (K=256: Q | red0 | red1) =================
    const int chunk = bk * 8 + w;            // 0..31
    const int b = chunk >> 2, rowbase = (chunk & 3) * 32;
    const int rgb = b * 128 + rowbase;
    #pragma unroll
    for (int tn = 0; tn < 10; ++tn) {
      const f32x4 ev = *(const f32x4*)(e1q + b * 160 + tn * 16 + nrow);
      acc[0][tn] = ev; acc[1][tn] = ev;
    }
    const f16x8* W1g = (const f16x8*)(wpk + OFF_QW1);
    #pragma unroll
    for (int c = 0; c < 8; ++c) {
      f16x8 x[2];
      #pragma unroll
      for (int tj = 0; tj < 2; ++tj) {
        const size_t row = (size_t)(rgb + tj * 16 + i);
        if (c < 4)      x[tj] = ld8(Q + row * 128 + c * 32 + g * 8);
        else if (c < 6) x[tj] = ld8max(red0p + row * 64 + (c - 4) * 32 + g * 8, 65536);
        else            x[tj] = ld8(red1 + row * 64 + (c - 6) * 32 + g * 8);
      }
      #pragma unroll
      for (int tn = 0; tn < 10; ++tn) {
        const f16x8 bf = W1g[(size_t)(c * 10 + tn) * 64 + lane];
        acc[0][tn] = MFMA16(bf, x[0], acc[0][tn]);
        acc[1][tn] = MFMA16(bf, x[1], acc[1][tn]);
      }
    }
    b2p = qb2; b3p = qb3;
    obase = outQ + (size_t)rgb * 64;
    rowlim = 32;
  } else {
    // ================= P branch L1 (K=256: qmax | P), 8 rows ===============
    if (w != 0) return;   // after the only barrier; safe
    #pragma unroll
    for (int tn = 0; tn < 10; ++tn) {
      const int nb = tn * 16 + nrow;
      f32x4 cv = {0.f, 0.f, 0.f, 0.f};
      if (nb < 132) cv = *(const f32x4*)(pb1 + nb);
      acc[0][tn] = cv; acc[1][tn] = cv;
    }
    const f16x8* W1g = (const f16x8*)(wpk + OFF_PW1);
    #pragma unroll
    for (int c = 0; c < 8; ++c) {
      f16x8 x[2];
      #pragma unroll
      for (int tj = 0; tj < 2; ++tj) {
        const int rr = (tj * 16 + i) & 7;
        const float* sp = (c < 4) ? (qmax + rr * 128 + c * 32 + g * 8)
                                  : (P + rr * 128 + (c - 4) * 32 + g * 8);
        x[tj] = ld8(sp);
      }
      #pragma unroll
      for (int tn = 0; tn < 10; ++tn) {
        const f16x8 bf = W1g[(size_t)(c * 10 + tn) * 64 + lane];
        acc[0][tn] = MFMA16(bf, x[0], acc[0][tn]);
        acc[1][tn] = MFMA16(bf, x[1], acc[1][tn]);
      }
    }
    b2p = pb2; b3p = pb3;
    obase = outP;
    rowlim = 8;
  }

  // ---- transition 1 (in-register) ----
  f16x8 hf[5][2];
  #pragma unroll
  for (int c5 = 0; c5 < 5; ++c5)
    #pragma unroll
    for (int tj = 0; tj < 2; ++tj)
      hf[c5][tj] = make_bfrag(acc[tj][2 * c5], acc[tj][2 * c5 + 1], srcA, srcB, glo);

  // ---- L2 (K=160), weights from LDS ----
  #pragma unroll
  for (int tn = 0; tn < 10; ++tn) {
    const int nb = tn * 16 + nrow;
    f32x4 bv = {0.f, 0.f, 0.f, 0.f};
    if (nb < 132) bv = *(const f32x4*)(b2p + nb);
    acc[0][tn] = bv; acc[1][tn] = bv;
  }
  #pragma unroll
  for (int c5 = 0; c5 < 5; ++c5)
    #pragma unroll
    for (int tn = 0; tn < 10; ++tn) {
      const f16x8 bf = W2L[(size_t)(c5 * 10 + tn) * 64 + lane];
      acc[0][tn] = MFMA16(bf, hf[c5][0], acc[0][tn]);
      acc[1][tn] = MFMA16(bf, hf[c5][1], acc[1][tn]);
    }

  // ---- transition 2 ----
  #pragma unroll
  for (int c5 = 0; c5 < 5; ++c5)
    #pragma unroll
    for (int tj = 0; tj < 2; ++tj)
      hf[c5][tj] = make_bfrag(acc[tj][2 * c5], acc[tj][2 * c5 + 1], srcA, srcB, glo);

  // ---- L3 (K=160, 64 out), weights from LDS ----
  f32x4 a3[2][4];
  #pragma unroll
  for (int tn = 0; tn < 4; ++tn) {
    const f32x4 bv = *(const f32x4*)(b3p + tn * 16 + nrow);
    a3[0][tn] = bv; a3[1][tn] = bv;
  }
  #pragma unroll
  for (int c5 = 0; c5 < 5; ++c5)
    #pragma unroll
    for (int tn = 0; tn < 4; ++tn) {
      const f16x8 bf = W3L[(size_t)(c5 * 4 + tn) * 64 + lane];
      a3[0][tn] = MFMA16(bf, hf[c5][0], a3[0][tn]);
      a3[1][tn] = MFMA16(bf, hf[c5][1], a3[1][tn]);
    }

  // ---- epilogue ----
  #pragma unroll
  for (int tj = 0; tj < 2; ++tj) {
    const int jr = tj * 16 + i;
    if (jr < rowlim) {
      #pragma unroll
      for (int tn = 0; tn < 4; ++tn) {
        f32x4 ov;
        #pragma unroll
        for (int r = 0; r < 4; ++r) ov[r] = sig5(a3[tj][tn][r]);
        *(f32x4*)(obase + (size_t)jr * 64 + tn * 16 + nrow) = ov;
      }
    }
  }
}

extern "C" void kernel_launch(void* const* d_in, const int* in_sizes, int n_in,
                              void* d_out, int out_size, void* d_ws, size_t ws_size,
                              hipStream_t stream) {
  (void)in_sizes; (void)n_in; (void)out_size; (void)ws_size;
  InPtrs ip;
  for (int i = 0; i < 21; ++i) ip.p[i] = (const float*)d_in[i];

  char* ws = (char*)d_ws;
  f16* wpk = (f16*)ws;
  float* wsf = (float*)(ws + PACK_BYTES);
  float* c1 = wsf;
  float* d1 = wsf + 163840;
  float* e1q = wsf + 327680;
  float* qmax = wsf + 328960;
  float* red0p = wsf + 329984;   // 2 x 65536 partials
  float* red1 = wsf + 461056;

  float* outP = (float*)d_out;
  float* outQ = outP + 512;
  float* outR = outP + 66048;

  prep_kernel<<<dim3(PREP_BLOCKS), dim3(256), 0, stream>>>(ip, wpk, c1, d1, e1q, qmax,
                                                           red0p, red1);
  fused_kernel<<<dim3(517), dim3(512), 0, stream>>>((const float*)d_in[2], c1, d1,
      (const float*)d_in[18], (const float*)d_in[20], wpk, outR,
      (const float*)d_in[0], (const float*)d_in[1],
      (const float*)d_in[12], (const float*)d_in[14],
      (const float*)d_in[4], (const float*)d_in[6], (const float*)d_in[8],
      e1q, qmax, red0p, red1, outP, outQ);
}